// Round 1
// 344.563 us; speedup vs baseline: 1.0894x; 1.0894x over previous
//
#include <hip/hip_runtime.h>
#include <hip/hip_bf16.h>
#include <math.h>

#define BB 32
#define TT 256
#define ZDIM 32

typedef float vf4 __attribute__((ext_vector_type(4)));
typedef short short8 __attribute__((ext_vector_type(8)));
typedef short short4v __attribute__((ext_vector_type(4)));
typedef float f32x4 __attribute__((ext_vector_type(4)));

__device__ __forceinline__ float softplus_f(float v) {
    return fmaxf(v, 0.0f) + log1pf(expf(-fabsf(v)));
}

__device__ __forceinline__ unsigned short f2bf(float f) {
    __hip_bfloat16 h = __float2bfloat16(f);
    return *reinterpret_cast<unsigned short*>(&h);
}

// ---------------- weight preconvert: W[o][ci][k] fp32 -> Wb[k][o][ci] bf16 ----------------
template<int COUT, int CIN>
__device__ void wconv_one(const float* __restrict__ W, unsigned short* __restrict__ Wb,
                          int tid, int nthreads)
{
    const int n = 3 * COUT * CIN;
    for (int idx = tid; idx < n; idx += nthreads) {
        int ci = idx % CIN;
        int q  = idx / CIN;
        int o  = q % COUT;
        int k  = q / COUT;
        Wb[idx] = f2bf(W[o * (CIN * 3) + ci * 3 + k]);
    }
}

__global__ __launch_bounds__(256)
void wconv_kernel(const float* __restrict__ W0, const float* __restrict__ W1,
                  const float* __restrict__ W2, unsigned short* __restrict__ w0b,
                  unsigned short* __restrict__ w1b, unsigned short* __restrict__ w2b)
{
    const int tid = blockIdx.x * blockDim.x + threadIdx.x;
    const int nth = gridDim.x * blockDim.x;
    wconv_one<256, 64>(W0, w0b, tid, nth);
    wconv_one<256, 256>(W1, w1b, tid, nth);
    wconv_one<96, 256>(W2, w2b, tid, nth);
}

// ---------------- bf16 MFMA conv ----------------
// out[o][t] += sum_ci W[o][ci][k] * x[ci][t+k-1] as 3 shifted GEMMs.
// Block = NW waves, wave = 16o x 64t strip, 16x16x32 bf16 MFMA.
// x staged in an 8-aligned window t in [t0-8, t0+71] (rows p = t-(t0-8), only
// p<=72 is ever read -> XROWS=73 keeps LDS at 62.7 KB). Global side of the
// staging is 16 B/lane vector loads (short8 / f32x4 x2); SAME-padding blocks
// are fully-in or fully-out of [0,TT) since TT,t0,window are 8-aligned.
// Fragment reads use row = nt*16+l15+ks+7.
// Epilogue (relu convs): wave-private bounce through this wave's wsb[0] rows
// (its af reads only ever touch rows [wv*16,wv*16+16), consumed long before),
// then 2x dwordx4 global stores per lane instead of 16x 2-byte scalars.
// Layouts (m89): A[m=lane&15][ci=quad*8+j], B[ci=quad*8+j][n=lane&15],
// C row = quad*4+reg, col = lane&15.
template<int CIN, int COUT, int NW, bool IS_STATS, bool XBF16>
__global__ __launch_bounds__(NW * 64)
void convm(const void* __restrict__ xin, const unsigned short* __restrict__ Wb,
           const float* __restrict__ bias, unsigned short* __restrict__ y,
           float* __restrict__ out_mu, float* __restrict__ dd,
           float* __restrict__ ss)
{
    constexpr int NT    = NW * 64;
    constexpr int OB    = NW * 16;
    constexpr int CT    = 64;
    constexpr int XPAD  = 72;   // 144 B rows: 16B-aligned b128 fragment reads
    constexpr int WPAD  = 68;   // 136 B rows: fits 64 KB at OB=128
    constexpr int XROWS = 73;   // staged rows actually consumed (p in [0,72])

    __shared__ unsigned short xsb[XROWS][XPAD];  // [p = t-(t0-8)][ci]
    __shared__ unsigned short wsb[3][OB][WPAD];  // [k][o][ci]

    const int b    = blockIdx.x;
    const int o0   = blockIdx.y * OB;
    const int t0   = blockIdx.z * 64;
    const int tid  = threadIdx.x;
    const int wv   = tid >> 6;
    const int lane = tid & 63;
    const int l15  = lane & 15;
    const int quad = lane >> 4;

    f32x4 acc[4];
    {
        f32x4 bv;
        #pragma unroll
        for (int r = 0; r < 4; ++r) bv[r] = bias[o0 + wv * 16 + quad * 4 + r];
        #pragma unroll
        for (int nt = 0; nt < 4; ++nt) acc[nt] = bv;
    }

    for (int c0 = 0; c0 < CIN; c0 += CT) {
        if (c0) __syncthreads();
        // stage x tile: vector global loads, transposed scalar LDS writes.
        // bf16 zero == 0x0000. 10 pv-blocks of 8 t cover [t0-8, t0+71].
        for (int idx = tid; idx < CT * 10; idx += NT) {
            int ci = idx / 10;
            int pv = idx - ci * 10;
            int t8 = t0 - 8 + pv * 8;
            unsigned short v[8];
            if (t8 >= 0 && t8 < TT) {
                if constexpr (XBF16) {
                    short8 xv = *(const short8*)((const unsigned short*)xin
                                 + (size_t)(b * CIN + c0 + ci) * TT + t8);
                    #pragma unroll
                    for (int j = 0; j < 8; ++j) v[j] = (unsigned short)xv[j];
                } else {
                    const float* xp = (const float*)xin
                                      + (size_t)(b * CIN + c0 + ci) * TT + t8;
                    f32x4 lo = *(const f32x4*)xp;
                    f32x4 hi = *(const f32x4*)(xp + 4);
                    #pragma unroll
                    for (int j = 0; j < 4; ++j) {
                        v[j]     = f2bf(lo[j]);
                        v[4 + j] = f2bf(hi[j]);
                    }
                }
            } else {
                #pragma unroll
                for (int j = 0; j < 8; ++j) v[j] = 0;
            }
            if (pv < 9) {
                #pragma unroll
                for (int j = 0; j < 8; ++j) xsb[pv * 8 + j][ci] = v[j];
            } else {
                xsb[72][ci] = v[0];   // p=72 (t = t0+64); rows 73..79 unused
            }
        }
        // stage weights: short4 (8 B) vector copies from Wb[k][o][ci]
        for (int idx = tid; idx < 3 * OB * (CT / 4); idx += NT) {
            int cv = idx % (CT / 4);
            int q  = idx / (CT / 4);
            int o  = q % OB;
            int k  = q / OB;
            short4v v = *(const short4v*)&Wb[((k * COUT) + o0 + o) * CIN + c0 + cv * 4];
            *(short4v*)&wsb[k][o][cv * 4] = v;
        }
        __syncthreads();

        #pragma unroll
        for (int ks = 0; ks < 3; ++ks) {
            #pragma unroll
            for (int kc = 0; kc < CT; kc += 32) {
                short8 af = *(const short8*)&wsb[ks][wv * 16 + l15][kc + quad * 8];
                #pragma unroll
                for (int nt = 0; nt < 4; ++nt) {
                    short8 bf = *(const short8*)&xsb[nt * 16 + l15 + ks + 7][kc + quad * 8];
                    acc[nt] = __builtin_amdgcn_mfma_f32_16x16x32_bf16(af, bf, acc[nt], 0, 0, 0);
                }
            }
        }
    }

    if constexpr (!IS_STATS) {
        // relu -> bf16, bounced through wave-private LDS rows, 16 B stores.
        // Rounding identical to the old scalar path (same f2bf before store).
        unsigned short (*eb)[WPAD] = (unsigned short (*)[WPAD])&wsb[0][wv * 16][0];
        #pragma unroll
        for (int nt = 0; nt < 4; ++nt) {
            #pragma unroll
            for (int r = 0; r < 4; ++r)
                eb[quad * 4 + r][nt * 16 + l15] = f2bf(fmaxf(acc[nt][r], 0.f));
        }
        // same-wave LDS RAW: compiler inserts lgkmcnt; no barrier needed.
        const int lr = lane >> 2;   // o-row within wave tile (0..15)
        const int lc = lane & 3;    // 16-wide t-chunk (0..3)
        short4v a0 = *(const short4v*)&eb[lr][lc * 16 + 0];
        short4v a1 = *(const short4v*)&eb[lr][lc * 16 + 4];
        short4v a2 = *(const short4v*)&eb[lr][lc * 16 + 8];
        short4v a3 = *(const short4v*)&eb[lr][lc * 16 + 12];
        short8 v0, v1;
        #pragma unroll
        for (int j = 0; j < 4; ++j) {
            v0[j] = a0[j]; v0[4 + j] = a1[j];
            v1[j] = a2[j]; v1[4 + j] = a3[j];
        }
        unsigned short* yp = y + (size_t)(b * COUT + o0 + wv * 16 + lr) * TT
                             + t0 + lc * 16;
        *(short8*)yp       = v0;
        *(short8*)(yp + 8) = v1;
    } else {
        // stats: o<32 -> mu (fp32); else softplus -> dd (even, +1) / ss (odd)
        #pragma unroll
        for (int nt = 0; nt < 4; ++nt) {
            int t = t0 + nt * 16 + l15;
            #pragma unroll
            for (int r = 0; r < 4; ++r) {
                int o = o0 + wv * 16 + quad * 4 + r;
                float val = acc[nt][r];
                if (o < ZDIM) {
                    out_mu[(b * ZDIM + o) * TT + t] = val;
                } else {
                    int oc = o - ZDIM;
                    int z  = oc >> 1;
                    float sp = softplus_f(val);
                    if ((oc & 1) == 0) dd[(b * ZDIM + z) * TT + t] = sp + 1.f;
                    else               ss[(b * ZDIM + z) * TT + t] = sp;
                }
            }
        }
    }
}

// ---------------- banded inverse-transpose ----------------
// scale_tril[r,c] = invd[r] * prod_{k=c}^{r-1} t_k (t_k = -s_k/d_k), 0 above diag.
// One 256-thread block per (b,z): 4 waves = 4 row-bands sharing one invd/tt
// load (dd/ss read once instead of 4x). Seed = prod_{k=c}^{r0-2} t_k computed
// per-wave (first in-band iter supplies t_{r0-1}); ascending order ->
// bit-identical to the 1-wave version.
__global__ __launch_bounds__(256)
void tril_kernel(const float* __restrict__ dd, const float* __restrict__ ss,
                 float* __restrict__ out)
{
    __shared__ float invd[TT];
    __shared__ float tt[TT];

    const int bz  = blockIdx.x;
    const int tid = threadIdx.x;

    {
        float d  = dd[bz * TT + tid];
        float s  = ss[bz * TT + tid];
        float iv = 1.0f / d;
        invd[tid] = iv;
        tt[tid]   = -s * iv;
    }
    __syncthreads();

    const int r0 = (tid >> 6) * 64;
    const int c0 = (tid & 63) * 4;

    float p0 = 1.f, p1 = 1.f, p2 = 1.f, p3 = 1.f;
    for (int k = 0; k < r0 - 1; ++k) {
        float tm = tt[k];
        p0 = (k >= c0    ) ? p0 * tm : p0;
        p1 = (k >= c0 + 1) ? p1 * tm : p1;
        p2 = (k >= c0 + 2) ? p2 * tm : p2;
        p3 = (k >= c0 + 3) ? p3 * tm : p3;
    }
    p0 = (c0     < r0) ? p0 : 0.f;
    p1 = (c0 + 1 < r0) ? p1 : 0.f;
    p2 = (c0 + 2 < r0) ? p2 : 0.f;
    p3 = (c0 + 3 < r0) ? p3 : 0.f;

    float* orow = out + (size_t)bz * TT * TT + (size_t)r0 * TT + c0;

    #pragma unroll 2
    for (int r = r0; r < r0 + 64; ++r) {
        float tm = (r > 0) ? tt[r - 1] : 0.0f;
        p0 = (r == c0    ) ? 1.0f : p0 * tm;
        p1 = (r == c0 + 1) ? 1.0f : p1 * tm;
        p2 = (r == c0 + 2) ? 1.0f : p2 * tm;
        p3 = (r == c0 + 3) ? 1.0f : p3 * tm;
        float id = invd[r];
        vf4 v;
        v.x = p0 * id; v.y = p1 * id; v.z = p2 * id; v.w = p3 * id;
        v.x = isfinite(v.x) ? v.x : 0.0f;
        v.y = isfinite(v.y) ? v.y : 0.0f;
        v.z = isfinite(v.z) ? v.z : 0.0f;
        v.w = isfinite(v.w) ? v.w : 0.0f;
        __builtin_nontemporal_store(v, (vf4*)orow);
        orow += TT;
    }
}

extern "C" void kernel_launch(void* const* d_in, const int* in_sizes, int n_in,
                              void* d_out, int out_size, void* d_ws, size_t ws_size,
                              hipStream_t stream)
{
    const float* x  = (const float*)d_in[0];
    const float* W0 = (const float*)d_in[1];
    const float* b0 = (const float*)d_in[2];
    const float* W1 = (const float*)d_in[3];
    const float* b1 = (const float*)d_in[4];
    const float* W2 = (const float*)d_in[5];
    const float* b2 = (const float*)d_in[6];

    float* out = (float*)d_out;
    float* mu  = out;                          // (32,32,256)
    float* st  = out + BB * ZDIM * TT;         // (32,32,256,256)

    // workspace layout (bf16 intermediates + fp32 dd/ss + bf16 weights)
    unsigned short* h0b = (unsigned short*)d_ws;          // 2,097,152 shorts (4 MB)
    unsigned short* h1b = h0b + BB * 256 * TT;            // 2,097,152 shorts
    float* dd  = (float*)(h1b + BB * 256 * TT);           // 262,144 floats
    float* ss  = dd + BB * ZDIM * TT;                     // 262,144 floats
    unsigned short* w0b = (unsigned short*)(ss + BB * ZDIM * TT);  // 3*256*64
    unsigned short* w1b = w0b + 3 * 256 * 64;                      // 3*256*256
    unsigned short* w2b = w1b + 3 * 256 * 256;                     // 3*96*256

    // weight preconvert + transpose to [k][o][ci] bf16
    wconv_kernel<<<dim3(256), 256, 0, stream>>>(W0, W1, W2, w0b, w1b, w2b);
    // conv1: 64 -> 256, relu (fp32 in, bf16 out); 8 waves, 128 o/block
    convm<64, 256, 8, false, false><<<dim3(BB, 2, 4), 512, 0, stream>>>(
        x, w0b, b0, h0b, nullptr, nullptr, nullptr);
    // conv2: 256 -> 256, relu (bf16 in/out); 8 waves, 128 o/block
    convm<256, 256, 8, false, true><<<dim3(BB, 2, 4), 512, 0, stream>>>(
        h0b, w1b, b1, h1b, nullptr, nullptr, nullptr);
    // conv3: 256 -> 96, stats (bf16 in, fp32 mu/dd/ss out); 3 waves, 48 o/block
    convm<256, 96, 3, true, true><<<dim3(BB, 2, 4), 192, 0, stream>>>(
        h1b, w2b, b2, nullptr, mu, dd, ss);
    // banded inverse-transpose, write-bound; 1 block = 4 bands per (b,z)
    tril_kernel<<<dim3(BB * ZDIM), 256, 0, stream>>>(dd, ss, st);
}

// Round 2
// 339.415 us; speedup vs baseline: 1.1059x; 1.0152x over previous
//
#include <hip/hip_runtime.h>
#include <hip/hip_bf16.h>
#include <math.h>

#define BB 32
#define TT 256
#define ZDIM 32

typedef float vf4 __attribute__((ext_vector_type(4)));
typedef short short8 __attribute__((ext_vector_type(8)));
typedef short short4v __attribute__((ext_vector_type(4)));
typedef float f32x4 __attribute__((ext_vector_type(4)));

__device__ __forceinline__ float softplus_f(float v) {
    return fmaxf(v, 0.0f) + log1pf(expf(-fabsf(v)));
}

__device__ __forceinline__ unsigned short f2bf(float f) {
    __hip_bfloat16 h = __float2bfloat16(f);
    return *reinterpret_cast<unsigned short*>(&h);
}

// ---------------- weight preconvert: W[o][ci][k] fp32 -> Wb[k][o][ci] bf16 ----------------
template<int COUT, int CIN>
__device__ void wconv_one(const float* __restrict__ W, unsigned short* __restrict__ Wb,
                          int tid, int nthreads)
{
    const int n = 3 * COUT * CIN;
    for (int idx = tid; idx < n; idx += nthreads) {
        int ci = idx % CIN;
        int q  = idx / CIN;
        int o  = q % COUT;
        int k  = q / COUT;
        Wb[idx] = f2bf(W[o * (CIN * 3) + ci * 3 + k]);
    }
}

__global__ __launch_bounds__(256)
void wconv_kernel(const float* __restrict__ W0, const float* __restrict__ W1,
                  const float* __restrict__ W2, unsigned short* __restrict__ w0b,
                  unsigned short* __restrict__ w1b, unsigned short* __restrict__ w2b)
{
    const int tid = blockIdx.x * blockDim.x + threadIdx.x;
    const int nth = gridDim.x * blockDim.x;
    wconv_one<256, 64>(W0, w0b, tid, nth);
    wconv_one<256, 256>(W1, w1b, tid, nth);
    wconv_one<96, 256>(W2, w2b, tid, nth);
}

// ---------------- bf16 MFMA conv ----------------
// out[o][t] += sum_ci W[o][ci][k] * x[ci][t+k-1] as 3 shifted GEMMs.
// Block = NW waves, wave = 16o x TTILE-t strip, 16x16x32 bf16 MFMA.
// GEOMETRY (round 2): OB=64 / NW=4 / TTILE=32 -> LDS 32.9 KB -> 4 blocks/CU
// (grid 1024). Round-1 evidence says the conv phase is latency-serialized at
// 1 block/CU (barrier stalls with no co-resident block); 4 blocks/CU lets
// other blocks compute through each block's stage barrier.
// x staged in an 8-aligned window t in [t0-8, t0+TTILE+7]; fragment reads use
// row p = nt*16+l15+ks+7. SAME-padding blocks are fully-in/out of [0,TT).
// Epilogue (relu convs): wave-private bounce through this wave's wsb[0] rows
// (its af reads only touch rows [wv*16,wv*16+16), consumed before), then one
// 16 B global store per lane.
// Layouts (m89): A[m=lane&15][ci=quad*8+j], B[ci=quad*8+j][n=lane&15],
// C row = quad*4+reg, col = lane&15.
template<int CIN, int COUT, int NW, int TTILE, bool IS_STATS, bool XBF16>
__global__ __launch_bounds__(NW * 64, 4)
void convm(const void* __restrict__ xin, const unsigned short* __restrict__ Wb,
           const float* __restrict__ bias, unsigned short* __restrict__ y,
           float* __restrict__ out_mu, float* __restrict__ dd,
           float* __restrict__ ss)
{
    static_assert(TTILE == 32, "epilogue lane mapping assumes TTILE=32");
    constexpr int NT    = NW * 64;
    constexpr int OB    = NW * 16;
    constexpr int CT    = 64;
    constexpr int NTF   = TTILE / 16;        // t-fragments per wave
    constexpr int PVN   = (TTILE + 16) / 8;  // 8-wide stage blocks
    constexpr int XROWS = TTILE + 16;        // rows allocated (reads use <= TTILE+8)
    constexpr int XPAD  = 72;   // 144 B rows: 16B-aligned b128 fragment reads
    constexpr int WPAD  = 68;   // 136 B rows: conflict-free af reads

    __shared__ unsigned short xsb[XROWS][XPAD];  // [p = t-(t0-8)][ci]
    __shared__ unsigned short wsb[3][OB][WPAD];  // [k][o][ci]

    const int b    = blockIdx.x;
    const int o0   = blockIdx.y * OB;
    const int t0   = blockIdx.z * TTILE;
    const int tid  = threadIdx.x;
    const int wv   = tid >> 6;
    const int lane = tid & 63;
    const int l15  = lane & 15;
    const int quad = lane >> 4;

    f32x4 acc[NTF];
    {
        f32x4 bv;
        #pragma unroll
        for (int r = 0; r < 4; ++r) bv[r] = bias[o0 + wv * 16 + quad * 4 + r];
        #pragma unroll
        for (int nt = 0; nt < NTF; ++nt) acc[nt] = bv;
    }

    for (int c0 = 0; c0 < CIN; c0 += CT) {
        if (c0) __syncthreads();
        // stage x tile: vector global loads, transposed scalar LDS writes.
        // bf16 zero == 0x0000. PVN pv-blocks of 8 t cover [t0-8, t0+TTILE+7].
        for (int idx = tid; idx < CT * PVN; idx += NT) {
            int ci = idx / PVN;
            int pv = idx - ci * PVN;
            int t8 = t0 - 8 + pv * 8;
            unsigned short v[8];
            if (t8 >= 0 && t8 < TT) {
                if constexpr (XBF16) {
                    short8 xv = *(const short8*)((const unsigned short*)xin
                                 + (size_t)(b * CIN + c0 + ci) * TT + t8);
                    #pragma unroll
                    for (int j = 0; j < 8; ++j) v[j] = (unsigned short)xv[j];
                } else {
                    const float* xp = (const float*)xin
                                      + (size_t)(b * CIN + c0 + ci) * TT + t8;
                    f32x4 lo = *(const f32x4*)xp;
                    f32x4 hi = *(const f32x4*)(xp + 4);
                    #pragma unroll
                    for (int j = 0; j < 4; ++j) {
                        v[j]     = f2bf(lo[j]);
                        v[4 + j] = f2bf(hi[j]);
                    }
                }
            } else {
                #pragma unroll
                for (int j = 0; j < 8; ++j) v[j] = 0;
            }
            #pragma unroll
            for (int j = 0; j < 8; ++j) xsb[pv * 8 + j][ci] = v[j];
        }
        // stage weights: short4 (8 B) vector copies from Wb[k][o][ci]
        for (int idx = tid; idx < 3 * OB * (CT / 4); idx += NT) {
            int cv = idx % (CT / 4);
            int q  = idx / (CT / 4);
            int o  = q % OB;
            int k  = q / OB;
            short4v v = *(const short4v*)&Wb[((k * COUT) + o0 + o) * CIN + c0 + cv * 4];
            *(short4v*)&wsb[k][o][cv * 4] = v;
        }
        __syncthreads();

        #pragma unroll
        for (int ks = 0; ks < 3; ++ks) {
            #pragma unroll
            for (int kc = 0; kc < CT; kc += 32) {
                short8 af = *(const short8*)&wsb[ks][wv * 16 + l15][kc + quad * 8];
                #pragma unroll
                for (int nt = 0; nt < NTF; ++nt) {
                    short8 bf = *(const short8*)&xsb[nt * 16 + l15 + ks + 7][kc + quad * 8];
                    acc[nt] = __builtin_amdgcn_mfma_f32_16x16x32_bf16(af, bf, acc[nt], 0, 0, 0);
                }
            }
        }
    }

    if constexpr (!IS_STATS) {
        // relu -> bf16, bounced through wave-private LDS rows, 16 B stores.
        // Rounding identical to scalar path (same f2bf before store).
        unsigned short (*eb)[WPAD] = (unsigned short (*)[WPAD])&wsb[0][wv * 16][0];
        #pragma unroll
        for (int nt = 0; nt < NTF; ++nt) {
            #pragma unroll
            for (int r = 0; r < 4; ++r)
                eb[quad * 4 + r][nt * 16 + l15] = f2bf(fmaxf(acc[nt][r], 0.f));
        }
        // same-wave LDS RAW: compiler inserts lgkmcnt; no barrier needed.
        const int lr = lane >> 2;   // o-row within wave tile (0..15)
        const int lc = lane & 3;    // 8-wide t-chunk (0..3)
        short4v a0 = *(const short4v*)&eb[lr][lc * 8 + 0];
        short4v a1 = *(const short4v*)&eb[lr][lc * 8 + 4];
        short8 v0;
        #pragma unroll
        for (int j = 0; j < 4; ++j) {
            v0[j] = a0[j]; v0[4 + j] = a1[j];
        }
        unsigned short* yp = y + (size_t)(b * COUT + o0 + wv * 16 + lr) * TT
                             + t0 + lc * 8;
        *(short8*)yp = v0;
    } else {
        // stats: o<32 -> mu (fp32); else softplus -> dd (even, +1) / ss (odd)
        #pragma unroll
        for (int nt = 0; nt < NTF; ++nt) {
            int t = t0 + nt * 16 + l15;
            #pragma unroll
            for (int r = 0; r < 4; ++r) {
                int o = o0 + wv * 16 + quad * 4 + r;
                float val = acc[nt][r];
                if (o < ZDIM) {
                    out_mu[(b * ZDIM + o) * TT + t] = val;
                } else {
                    int oc = o - ZDIM;
                    int z  = oc >> 1;
                    float sp = softplus_f(val);
                    if ((oc & 1) == 0) dd[(b * ZDIM + z) * TT + t] = sp + 1.f;
                    else               ss[(b * ZDIM + z) * TT + t] = sp;
                }
            }
        }
    }
}

// ---------------- banded inverse-transpose ----------------
// scale_tril[r,c] = invd[r] * prod_{k=c}^{r-1} t_k (t_k = -s_k/d_k), 0 above diag.
// One 256-thread block per (b,z): 4 waves = 4 row-bands sharing one invd/tt
// load. Seed = prod_{k=c}^{r0-2} t_k per-wave; ascending order -> bit-identical
// to the 1-wave version.
__global__ __launch_bounds__(256)
void tril_kernel(const float* __restrict__ dd, const float* __restrict__ ss,
                 float* __restrict__ out)
{
    __shared__ float invd[TT];
    __shared__ float tt[TT];

    const int bz  = blockIdx.x;
    const int tid = threadIdx.x;

    {
        float d  = dd[bz * TT + tid];
        float s  = ss[bz * TT + tid];
        float iv = 1.0f / d;
        invd[tid] = iv;
        tt[tid]   = -s * iv;
    }
    __syncthreads();

    const int r0 = (tid >> 6) * 64;
    const int c0 = (tid & 63) * 4;

    float p0 = 1.f, p1 = 1.f, p2 = 1.f, p3 = 1.f;
    for (int k = 0; k < r0 - 1; ++k) {
        float tm = tt[k];
        p0 = (k >= c0    ) ? p0 * tm : p0;
        p1 = (k >= c0 + 1) ? p1 * tm : p1;
        p2 = (k >= c0 + 2) ? p2 * tm : p2;
        p3 = (k >= c0 + 3) ? p3 * tm : p3;
    }
    p0 = (c0     < r0) ? p0 : 0.f;
    p1 = (c0 + 1 < r0) ? p1 : 0.f;
    p2 = (c0 + 2 < r0) ? p2 : 0.f;
    p3 = (c0 + 3 < r0) ? p3 : 0.f;

    float* orow = out + (size_t)bz * TT * TT + (size_t)r0 * TT + c0;

    #pragma unroll 2
    for (int r = r0; r < r0 + 64; ++r) {
        float tm = (r > 0) ? tt[r - 1] : 0.0f;
        p0 = (r == c0    ) ? 1.0f : p0 * tm;
        p1 = (r == c0 + 1) ? 1.0f : p1 * tm;
        p2 = (r == c0 + 2) ? 1.0f : p2 * tm;
        p3 = (r == c0 + 3) ? 1.0f : p3 * tm;
        float id = invd[r];
        vf4 v;
        v.x = p0 * id; v.y = p1 * id; v.z = p2 * id; v.w = p3 * id;
        v.x = isfinite(v.x) ? v.x : 0.0f;
        v.y = isfinite(v.y) ? v.y : 0.0f;
        v.z = isfinite(v.z) ? v.z : 0.0f;
        v.w = isfinite(v.w) ? v.w : 0.0f;
        __builtin_nontemporal_store(v, (vf4*)orow);
        orow += TT;
    }
}

extern "C" void kernel_launch(void* const* d_in, const int* in_sizes, int n_in,
                              void* d_out, int out_size, void* d_ws, size_t ws_size,
                              hipStream_t stream)
{
    const float* x  = (const float*)d_in[0];
    const float* W0 = (const float*)d_in[1];
    const float* b0 = (const float*)d_in[2];
    const float* W1 = (const float*)d_in[3];
    const float* b1 = (const float*)d_in[4];
    const float* W2 = (const float*)d_in[5];
    const float* b2 = (const float*)d_in[6];

    float* out = (float*)d_out;
    float* mu  = out;                          // (32,32,256)
    float* st  = out + BB * ZDIM * TT;         // (32,32,256,256)

    // workspace layout (bf16 intermediates + fp32 dd/ss + bf16 weights)
    unsigned short* h0b = (unsigned short*)d_ws;          // 2,097,152 shorts (4 MB)
    unsigned short* h1b = h0b + BB * 256 * TT;            // 2,097,152 shorts
    float* dd  = (float*)(h1b + BB * 256 * TT);           // 262,144 floats
    float* ss  = dd + BB * ZDIM * TT;                     // 262,144 floats
    unsigned short* w0b = (unsigned short*)(ss + BB * ZDIM * TT);  // 3*256*64
    unsigned short* w1b = w0b + 3 * 256 * 64;                      // 3*256*256
    unsigned short* w2b = w1b + 3 * 256 * 256;                     // 3*96*256

    // weight preconvert + transpose to [k][o][ci] bf16
    wconv_kernel<<<dim3(256), 256, 0, stream>>>(W0, W1, W2, w0b, w1b, w2b);
    // conv1: 64 -> 256, relu (fp32 in, bf16 out); 4 waves, 64 o, 32 t / block
    convm<64, 256, 4, 32, false, false><<<dim3(BB, 4, 8), 256, 0, stream>>>(
        x, w0b, b0, h0b, nullptr, nullptr, nullptr);
    // conv2: 256 -> 256, relu (bf16 in/out); 4 waves, 64 o, 32 t / block
    convm<256, 256, 4, 32, false, true><<<dim3(BB, 4, 8), 256, 0, stream>>>(
        h0b, w1b, b1, h1b, nullptr, nullptr, nullptr);
    // conv3: 256 -> 96, stats (bf16 in, fp32 mu/dd/ss out); 3 waves, 48 o, 32 t
    convm<256, 96, 3, 32, true, true><<<dim3(BB, 2, 8), 192, 0, stream>>>(
        h1b, w2b, b2, nullptr, mu, dd, ss);
    // banded inverse-transpose, write-bound; 1 block = 4 bands per (b,z)
    tril_kernel<<<dim3(BB * ZDIM), 256, 0, stream>>>(dd, ss, st);
}

// Round 3
// 321.075 us; speedup vs baseline: 1.1691x; 1.0571x over previous
//
#include <hip/hip_runtime.h>
#include <hip/hip_bf16.h>
#include <math.h>

#define BB 32
#define TT 256
#define ZDIM 32

typedef float vf4 __attribute__((ext_vector_type(4)));
typedef short short8 __attribute__((ext_vector_type(8)));
typedef short short4v __attribute__((ext_vector_type(4)));
typedef float f32x4 __attribute__((ext_vector_type(4)));

__device__ __forceinline__ float softplus_f(float v) {
    return fmaxf(v, 0.0f) + log1pf(expf(-fabsf(v)));
}

__device__ __forceinline__ unsigned short f2bf(float f) {
    __hip_bfloat16 h = __float2bfloat16(f);
    return *reinterpret_cast<unsigned short*>(&h);
}

// ---------------- weight preconvert: W[o][ci][k] fp32 -> Wb[k][o][ci] bf16 ----------------
template<int COUT, int CIN>
__device__ void wconv_one(const float* __restrict__ W, unsigned short* __restrict__ Wb,
                          int tid, int nthreads)
{
    const int n = 3 * COUT * CIN;
    for (int idx = tid; idx < n; idx += nthreads) {
        int ci = idx % CIN;
        int q  = idx / CIN;
        int o  = q % COUT;
        int k  = q / COUT;
        Wb[idx] = f2bf(W[o * (CIN * 3) + ci * 3 + k]);
    }
}

__global__ __launch_bounds__(256)
void wconv_kernel(const float* __restrict__ W0, const float* __restrict__ W1,
                  const float* __restrict__ W2, unsigned short* __restrict__ w0b,
                  unsigned short* __restrict__ w1b, unsigned short* __restrict__ w2b)
{
    const int tid = blockIdx.x * blockDim.x + threadIdx.x;
    const int nth = gridDim.x * blockDim.x;
    wconv_one<256, 64>(W0, w0b, tid, nth);
    wconv_one<256, 256>(W1, w1b, tid, nth);
    wconv_one<96, 256>(W2, w2b, tid, nth);
}

// ---------------- bf16 MFMA conv ----------------
// out[o][t] += sum_ci W[o][ci][k] * x[ci][t+k-1] as 3 shifted GEMMs.
// Block = NW waves, wave = 16o x TTILE-t strip, 16x16x32 bf16 MFMA.
// ROUND 3: weights are NOT LDS-staged. Wb is [k][o][ci] = fragment order, so
// each wave loads its A-fragment directly from global as one 16 B/lane L2-hit
// load (weights <=393 KB, L2-resident, ~100 MB aggregate fragment traffic
// ~3 us at L2 BW). This deletes the per-c0 weight staging loop (~12 copies/
// thread), one barrier-coupled phase, and 55 KB of LDS (6.9 KB left).
// x stays LDS-transposed (fragment needs 8 consecutive ci per t: global
// [ci][t] layout can't deliver that as a vector load).
// x staged in an 8-aligned window t in [t0-8, t0+TTILE+7]; fragment reads use
// row p = nt*16+l15+ks+7. SAME-padding blocks are fully-in/out of [0,TT).
// Epilogue (relu convs): after one barrier, bounce the wave's 16x32 bf16 tile
// through flat xsb (wave-private 512-short slice), then one 16 B store/lane.
// Layouts (m89): A[m=lane&15][ci=quad*8+j], B[ci=quad*8+j][n=lane&15],
// C row = quad*4+reg, col = lane&15.
template<int CIN, int COUT, int NW, int TTILE, bool IS_STATS, bool XBF16>
__global__ __launch_bounds__(NW * 64, 6)
void convm(const void* __restrict__ xin, const unsigned short* __restrict__ Wb,
           const float* __restrict__ bias, unsigned short* __restrict__ y,
           float* __restrict__ out_mu, float* __restrict__ dd,
           float* __restrict__ ss)
{
    static_assert(TTILE == 32, "epilogue lane mapping assumes TTILE=32");
    constexpr int NT    = NW * 64;
    constexpr int OB    = NW * 16;
    constexpr int CT    = 64;
    constexpr int NTF   = TTILE / 16;        // t-fragments per wave
    constexpr int PVN   = (TTILE + 16) / 8;  // 8-wide stage blocks
    constexpr int XROWS = TTILE + 16;        // rows allocated (reads use <= TTILE+8)
    constexpr int XPAD  = 72;   // 144 B rows: 16B-aligned b128 fragment reads

    __shared__ __attribute__((aligned(16))) unsigned short xsb[XROWS][XPAD]; // [p][ci]

    const int b    = blockIdx.x;
    const int o0   = blockIdx.y * OB;
    const int t0   = blockIdx.z * TTILE;
    const int tid  = threadIdx.x;
    const int wv   = tid >> 6;
    const int lane = tid & 63;
    const int l15  = lane & 15;
    const int quad = lane >> 4;

    f32x4 acc[NTF];
    {
        f32x4 bv;
        #pragma unroll
        for (int r = 0; r < 4; ++r) bv[r] = bias[o0 + wv * 16 + quad * 4 + r];
        #pragma unroll
        for (int nt = 0; nt < NTF; ++nt) acc[nt] = bv;
    }

    // global base row for this wave's A-fragments: o = o0 + wv*16 + l15
    const unsigned short* wrow = Wb + (size_t)(o0 + wv * 16 + l15) * CIN;

    for (int c0 = 0; c0 < CIN; c0 += CT) {
        if (c0) __syncthreads();
        // stage x tile: vector global loads, transposed scalar LDS writes.
        // bf16 zero == 0x0000. PVN pv-blocks of 8 t cover [t0-8, t0+TTILE+7].
        for (int idx = tid; idx < CT * PVN; idx += NT) {
            int ci = idx / PVN;
            int pv = idx - ci * PVN;
            int t8 = t0 - 8 + pv * 8;
            unsigned short v[8];
            if (t8 >= 0 && t8 < TT) {
                if constexpr (XBF16) {
                    short8 xv = *(const short8*)((const unsigned short*)xin
                                 + (size_t)(b * CIN + c0 + ci) * TT + t8);
                    #pragma unroll
                    for (int j = 0; j < 8; ++j) v[j] = (unsigned short)xv[j];
                } else {
                    const float* xp = (const float*)xin
                                      + (size_t)(b * CIN + c0 + ci) * TT + t8;
                    f32x4 lo = *(const f32x4*)xp;
                    f32x4 hi = *(const f32x4*)(xp + 4);
                    #pragma unroll
                    for (int j = 0; j < 4; ++j) {
                        v[j]     = f2bf(lo[j]);
                        v[4 + j] = f2bf(hi[j]);
                    }
                }
            } else {
                #pragma unroll
                for (int j = 0; j < 8; ++j) v[j] = 0;
            }
            #pragma unroll
            for (int j = 0; j < 8; ++j) xsb[pv * 8 + j][ci] = v[j];
        }
        __syncthreads();

        #pragma unroll
        for (int ks = 0; ks < 3; ++ks) {
            #pragma unroll
            for (int kc = 0; kc < CT; kc += 32) {
                // A-fragment direct from global (L2-hit, 16 B/lane, aligned)
                short8 af = *(const short8*)(wrow + (size_t)ks * COUT * CIN
                                             + c0 + kc + quad * 8);
                #pragma unroll
                for (int nt = 0; nt < NTF; ++nt) {
                    short8 bf = *(const short8*)&xsb[nt * 16 + l15 + ks + 7][kc + quad * 8];
                    acc[nt] = __builtin_amdgcn_mfma_f32_16x16x32_bf16(af, bf, acc[nt], 0, 0, 0);
                }
            }
        }
    }

    if constexpr (!IS_STATS) {
        // relu -> bf16, bounced through flat xsb (wave-private 512-short
        // slice), then one 16 B store per lane. Barrier first: xsb rows are
        // still MFMA-source for other waves until they finish the last c0.
        __syncthreads();
        unsigned short* eb = &xsb[0][0];
        const int base = wv * 512;   // 16 rows x 32 cols per wave
        #pragma unroll
        for (int nt = 0; nt < NTF; ++nt) {
            #pragma unroll
            for (int r = 0; r < 4; ++r)
                eb[base + (quad * 4 + r) * 32 + nt * 16 + l15] =
                    f2bf(fmaxf(acc[nt][r], 0.f));
        }
        // same-wave LDS RAW: compiler inserts lgkmcnt; no barrier needed.
        const int lr = lane >> 2;   // o-row within wave tile (0..15)
        const int lc = lane & 3;    // 8-wide t-chunk (0..3)
        short4v a0 = *(const short4v*)&eb[base + lr * 32 + lc * 8];
        short4v a1 = *(const short4v*)&eb[base + lr * 32 + lc * 8 + 4];
        short8 v0;
        #pragma unroll
        for (int j = 0; j < 4; ++j) {
            v0[j] = a0[j]; v0[4 + j] = a1[j];
        }
        unsigned short* yp = y + (size_t)(b * COUT + o0 + wv * 16 + lr) * TT
                             + t0 + lc * 8;
        *(short8*)yp = v0;
    } else {
        // stats: o<32 -> mu (fp32); else softplus -> dd (even, +1) / ss (odd)
        #pragma unroll
        for (int nt = 0; nt < NTF; ++nt) {
            int t = t0 + nt * 16 + l15;
            #pragma unroll
            for (int r = 0; r < 4; ++r) {
                int o = o0 + wv * 16 + quad * 4 + r;
                float val = acc[nt][r];
                if (o < ZDIM) {
                    out_mu[(b * ZDIM + o) * TT + t] = val;
                } else {
                    int oc = o - ZDIM;
                    int z  = oc >> 1;
                    float sp = softplus_f(val);
                    if ((oc & 1) == 0) dd[(b * ZDIM + z) * TT + t] = sp + 1.f;
                    else               ss[(b * ZDIM + z) * TT + t] = sp;
                }
            }
        }
    }
}

// ---------------- banded inverse-transpose ----------------
// scale_tril[r,c] = invd[r] * prod_{k=c}^{r-1} t_k (t_k = -s_k/d_k), 0 above diag.
// One 256-thread block per (b,z): 4 waves = 4 row-bands sharing one invd/tt
// load. Seed = prod_{k=c}^{r0-2} t_k per-wave; ascending order -> bit-identical
// to the 1-wave version. Write-bound: 268 MB fp32 out, ~43 us floor.
__global__ __launch_bounds__(256)
void tril_kernel(const float* __restrict__ dd, const float* __restrict__ ss,
                 float* __restrict__ out)
{
    __shared__ float invd[TT];
    __shared__ float tt[TT];

    const int bz  = blockIdx.x;
    const int tid = threadIdx.x;

    {
        float d  = dd[bz * TT + tid];
        float s  = ss[bz * TT + tid];
        float iv = 1.0f / d;
        invd[tid] = iv;
        tt[tid]   = -s * iv;
    }
    __syncthreads();

    const int r0 = (tid >> 6) * 64;
    const int c0 = (tid & 63) * 4;

    float p0 = 1.f, p1 = 1.f, p2 = 1.f, p3 = 1.f;
    for (int k = 0; k < r0 - 1; ++k) {
        float tm = tt[k];
        p0 = (k >= c0    ) ? p0 * tm : p0;
        p1 = (k >= c0 + 1) ? p1 * tm : p1;
        p2 = (k >= c0 + 2) ? p2 * tm : p2;
        p3 = (k >= c0 + 3) ? p3 * tm : p3;
    }
    p0 = (c0     < r0) ? p0 : 0.f;
    p1 = (c0 + 1 < r0) ? p1 : 0.f;
    p2 = (c0 + 2 < r0) ? p2 : 0.f;
    p3 = (c0 + 3 < r0) ? p3 : 0.f;

    float* orow = out + (size_t)bz * TT * TT + (size_t)r0 * TT + c0;

    #pragma unroll 2
    for (int r = r0; r < r0 + 64; ++r) {
        float tm = (r > 0) ? tt[r - 1] : 0.0f;
        p0 = (r == c0    ) ? 1.0f : p0 * tm;
        p1 = (r == c0 + 1) ? 1.0f : p1 * tm;
        p2 = (r == c0 + 2) ? 1.0f : p2 * tm;
        p3 = (r == c0 + 3) ? 1.0f : p3 * tm;
        float id = invd[r];
        vf4 v;
        v.x = p0 * id; v.y = p1 * id; v.z = p2 * id; v.w = p3 * id;
        v.x = isfinite(v.x) ? v.x : 0.0f;
        v.y = isfinite(v.y) ? v.y : 0.0f;
        v.z = isfinite(v.z) ? v.z : 0.0f;
        v.w = isfinite(v.w) ? v.w : 0.0f;
        __builtin_nontemporal_store(v, (vf4*)orow);
        orow += TT;
    }
}

extern "C" void kernel_launch(void* const* d_in, const int* in_sizes, int n_in,
                              void* d_out, int out_size, void* d_ws, size_t ws_size,
                              hipStream_t stream)
{
    const float* x  = (const float*)d_in[0];
    const float* W0 = (const float*)d_in[1];
    const float* b0 = (const float*)d_in[2];
    const float* W1 = (const float*)d_in[3];
    const float* b1 = (const float*)d_in[4];
    const float* W2 = (const float*)d_in[5];
    const float* b2 = (const float*)d_in[6];

    float* out = (float*)d_out;
    float* mu  = out;                          // (32,32,256)
    float* st  = out + BB * ZDIM * TT;         // (32,32,256,256)

    // workspace layout (bf16 intermediates + fp32 dd/ss + bf16 weights)
    unsigned short* h0b = (unsigned short*)d_ws;          // 2,097,152 shorts (4 MB)
    unsigned short* h1b = h0b + BB * 256 * TT;            // 2,097,152 shorts
    float* dd  = (float*)(h1b + BB * 256 * TT);           // 262,144 floats
    float* ss  = dd + BB * ZDIM * TT;                     // 262,144 floats
    unsigned short* w0b = (unsigned short*)(ss + BB * ZDIM * TT);  // 3*256*64
    unsigned short* w1b = w0b + 3 * 256 * 64;                      // 3*256*256
    unsigned short* w2b = w1b + 3 * 256 * 256;                     // 3*96*256

    // weight preconvert + transpose to [k][o][ci] bf16 (fragment order)
    wconv_kernel<<<dim3(256), 256, 0, stream>>>(W0, W1, W2, w0b, w1b, w2b);
    // conv1: 64 -> 256, relu (fp32 in, bf16 out); 4 waves, 64 o, 32 t / block
    convm<64, 256, 4, 32, false, false><<<dim3(BB, 4, 8), 256, 0, stream>>>(
        x, w0b, b0, h0b, nullptr, nullptr, nullptr);
    // conv2: 256 -> 256, relu (bf16 in/out); 4 waves, 64 o, 32 t / block
    convm<256, 256, 4, 32, false, true><<<dim3(BB, 4, 8), 256, 0, stream>>>(
        h0b, w1b, b1, h1b, nullptr, nullptr, nullptr);
    // conv3: 256 -> 96, stats (bf16 in, fp32 mu/dd/ss out); 3 waves, 48 o, 32 t
    convm<256, 96, 3, 32, true, true><<<dim3(BB, 2, 8), 192, 0, stream>>>(
        h1b, w2b, b2, nullptr, mu, dd, ss);
    // banded inverse-transpose, write-bound; 1 block = 4 bands per (b,z)
    tril_kernel<<<dim3(BB * ZDIM), 256, 0, stream>>>(dd, ss, st);
}